// Round 16
// baseline (828.194 us; speedup 1.0000x reference)
//
#include <hip/hip_runtime.h>
#include <hip/hip_cooperative_groups.h>
#include <math.h>

namespace cg = cooperative_groups;

#define B_  2
#define L_  2000
#define DM_ 256
#define DI_ 512
#define DS_ 16
#define NL_ 4
#define BL_ (B_*L_)     // 4000
#define BLP_ 4096       // rows padded to multiple of 64
#define NC_ 125         // scan chunks == conv strips (CL=16)
#define CL_ 16          // chunk length == conv_xproj strip

typedef unsigned short ushort_t;
typedef __attribute__((ext_vector_type(8))) short bf16x8;
typedef __attribute__((ext_vector_type(4))) float f32x4;

__device__ __forceinline__ float siluf(float x) {
    return x / (1.f + __expf(-x));
}

__device__ __forceinline__ ushort_t f2bf(float x) {
    unsigned int u = __float_as_uint(x);
    unsigned int r = (u + 0x7FFFu + ((u >> 16) & 1u)) >> 16;
    return (ushort_t)r;
}

__device__ __forceinline__ float bf2f(ushort_t v) {
    return __uint_as_float(((unsigned int)v) << 16);
}

// ---------------- fp32 -> bf16 conversion, 3 segments in one launch ----------------
__global__ __launch_bounds__(256) void f2bf3_kernel(
    const float* __restrict__ s0, const float* __restrict__ s1,
    const float* __restrict__ s2, ushort_t* __restrict__ d0,
    ushort_t* __restrict__ d1, ushort_t* __restrict__ d2,
    int N0, int N1, int N2)
{
    int i = blockIdx.x*256 + threadIdx.x;
    const float* s; ushort_t* d; int j;
    if (i < N0)           { s = s0; d = d0; j = i; }
    else if (i < N0+N1)   { s = s1; d = d1; j = i - N0; }
    else if (i < N0+N1+N2){ s = s2; d = d2; j = i - N0 - N1; }
    else return;
    float4 v = *(const float4*)(s + 4*j);
    ushort_t o[4] = {f2bf(v.x), f2bf(v.y), f2bf(v.z), f2bf(v.w)};
    *(ushort2*)(d + 4*j)     = *(ushort2*)&o[0];
    *(ushort2*)(d + 4*j + 2) = *(ushort2*)&o[2];
}

// ---------------- embed: h = x*biw + bib + ge + me; emit row LN stats ----------------
__global__ __launch_bounds__(256) void embed_kernel(
    const float* __restrict__ x, const float* __restrict__ biw,
    const float* __restrict__ bib, const float* __restrict__ ge,
    const float* __restrict__ me, float* __restrict__ h,
    float2* __restrict__ stats)
{
    __shared__ float sm[8];
    int bl = blockIdx.x, d = threadIdx.x;
    int l = bl % L_;
    float v = x[bl]*biw[d] + bib[d] + ge[(size_t)l*DM_ + d] + me[d];
    h[(size_t)bl*DM_ + d] = v;
    float s = v, q = v*v;
    #pragma unroll
    for (int o = 32; o > 0; o >>= 1) {
        s += __shfl_down(s, o);
        q += __shfl_down(q, o);
    }
    if ((d & 63) == 0) { sm[d >> 6] = s; sm[4 + (d >> 6)] = q; }
    __syncthreads();
    if (d == 0) {
        stats[bl] = make_float2(sm[0]+sm[1]+sm[2]+sm[3], sm[4]+sm[5]+sm[6]+sm[7]);
        stats[BLP_ + bl]   = make_float2(0.f, 0.f);
        stats[2*BLP_ + bl] = make_float2(0.f, 0.f);
        stats[3*BLP_ + bl] = make_float2(0.f, 0.f);
    }
}

// ---------------- fused LN + in_proj MFMA GEMM ----------------
__global__ __launch_bounds__(256) void gemm_ln_mfma(
    const float* __restrict__ H, const float2* __restrict__ stats,
    const float* __restrict__ lnw, const float* __restrict__ lnb,
    const ushort_t* __restrict__ W, ushort_t* __restrict__ C, int ldc)
{
    __shared__ ushort_t a_s[128*64];
    __shared__ ushort_t b_s[128*64];
    const int r0 = blockIdx.x*128, c0 = blockIdx.y*128;
    const int tid = threadIdx.x;
    const int lane = tid & 63, w = tid >> 6;
    const int wm = (w & 1)*64, wn = (w >> 1)*64;
    const int qd = lane >> 4, l16 = lane & 15;
    f32x4 acc[4][4] = {};
    for (int kc = 0; kc < DM_; kc += 64) {
        #pragma unroll
        for (int q = 0; q < 4; q++) {
            int ch = tid + 256*q;              // 0..1023
            int row = ch >> 3, col8 = (ch & 7)*8;
            int grow = r0 + row;
            float2 t0 = stats[grow], t1 = stats[BLP_ + grow];
            float2 t2 = stats[2*BLP_ + grow], t3 = stats[3*BLP_ + grow];
            float sum = t0.x + t1.x + t2.x + t3.x;
            float ssq = t0.y + t1.y + t2.y + t3.y;
            float mu  = sum * (1.f/DM_);
            float inv = rsqrtf(fmaxf(ssq*(1.f/DM_) - mu*mu, 0.f) + 1e-5f);
            const float* hp = H + (size_t)grow*DM_ + kc + col8;
            float4 h0 = *(const float4*)hp, h1 = *(const float4*)(hp + 4);
            const float* wp = lnw + kc + col8;
            const float* bp = lnb + kc + col8;
            float4 w0 = *(const float4*)wp, w1 = *(const float4*)(wp + 4);
            float4 b0 = *(const float4*)bp, b1 = *(const float4*)(bp + 4);
            __align__(16) ushort_t o[8];
            o[0] = f2bf((h0.x - mu)*inv*w0.x + b0.x);
            o[1] = f2bf((h0.y - mu)*inv*w0.y + b0.y);
            o[2] = f2bf((h0.z - mu)*inv*w0.z + b0.z);
            o[3] = f2bf((h0.w - mu)*inv*w0.w + b0.w);
            o[4] = f2bf((h1.x - mu)*inv*w1.x + b1.x);
            o[5] = f2bf((h1.y - mu)*inv*w1.y + b1.y);
            o[6] = f2bf((h1.z - mu)*inv*w1.z + b1.z);
            o[7] = f2bf((h1.w - mu)*inv*w1.w + b1.w);
            *(uint4*)&a_s[row*64 + col8] = *(const uint4*)o;
            *(bf16x8*)&b_s[row*64 + col8] =
                *(const bf16x8*)(W + (size_t)(c0 + row)*DM_ + kc + col8);
        }
        __syncthreads();
        #pragma unroll
        for (int ks = 0; ks < 2; ks++) {
            bf16x8 af[4], bf[4];
            #pragma unroll
            for (int i = 0; i < 4; i++)
                af[i] = *(const bf16x8*)&a_s[(wm + i*16 + l16)*64 + ks*32 + qd*8];
            #pragma unroll
            for (int j = 0; j < 4; j++)
                bf[j] = *(const bf16x8*)&b_s[(wn + j*16 + l16)*64 + ks*32 + qd*8];
            #pragma unroll
            for (int i = 0; i < 4; i++) {
                #pragma unroll
                for (int j = 0; j < 4; j++)
                    acc[i][j] = __builtin_amdgcn_mfma_f32_16x16x32_bf16(
                        af[i], bf[j], acc[i][j], 0, 0, 0);
            }
        }
        __syncthreads();
    }
    #pragma unroll
    for (int i = 0; i < 4; i++) {
        #pragma unroll
        for (int j = 0; j < 4; j++) {
            #pragma unroll
            for (int r = 0; r < 4; r++) {
                int row = r0 + wm + i*16 + qd*4 + r;
                int col = c0 + wn + j*16 + l16;
                C[(size_t)row*ldc + col] = f2bf(acc[i][j][r]);
            }
        }
    }
}

// ---------------- out_proj MFMA GEMM with h += and LN-stats epilogue ----------------
__global__ __launch_bounds__(256) void gemm_out_mfma(
    const ushort_t* __restrict__ A, const ushort_t* __restrict__ W,
    float* __restrict__ C, int ldc, int K, float2* __restrict__ stp)
{
    __shared__ ushort_t a_s[128*64];
    __shared__ ushort_t b_s[128*64];
    const int r0 = blockIdx.x*128, c0 = blockIdx.y*128;
    const int tid = threadIdx.x;
    const int lane = tid & 63, w = tid >> 6;
    const int wm = (w & 1)*64, wn = (w >> 1)*64;
    const int qd = lane >> 4, l16 = lane & 15;
    f32x4 acc[4][4] = {};
    for (int kc = 0; kc < K; kc += 64) {
        #pragma unroll
        for (int q = 0; q < 4; q++) {
            int ch = tid + 256*q;
            int row = ch >> 3, col8 = (ch & 7)*8;
            *(bf16x8*)&a_s[row*64 + col8] =
                *(const bf16x8*)(A + (size_t)(r0 + row)*K + kc + col8);
            *(bf16x8*)&b_s[row*64 + col8] =
                *(const bf16x8*)(W + (size_t)(c0 + row)*K + kc + col8);
        }
        __syncthreads();
        #pragma unroll
        for (int ks = 0; ks < 2; ks++) {
            bf16x8 af[4], bf[4];
            #pragma unroll
            for (int i = 0; i < 4; i++)
                af[i] = *(const bf16x8*)&a_s[(wm + i*16 + l16)*64 + ks*32 + qd*8];
            #pragma unroll
            for (int j = 0; j < 4; j++)
                bf[j] = *(const bf16x8*)&b_s[(wn + j*16 + l16)*64 + ks*32 + qd*8];
            #pragma unroll
            for (int i = 0; i < 4; i++) {
                #pragma unroll
                for (int j = 0; j < 4; j++)
                    acc[i][j] = __builtin_amdgcn_mfma_f32_16x16x32_bf16(
                        af[i], bf[j], acc[i][j], 0, 0, 0);
            }
        }
        __syncthreads();
    }
    const int slot = blockIdx.y*2 + (w >> 1);
    #pragma unroll
    for (int i = 0; i < 4; i++) {
        #pragma unroll
        for (int r = 0; r < 4; r++) {
            int row = r0 + wm + i*16 + qd*4 + r;
            float sum = 0.f, ssq = 0.f;
            #pragma unroll
            for (int j = 0; j < 4; j++) {
                int col = c0 + wn + j*16 + l16;
                size_t idx = (size_t)row*ldc + col;
                float v = C[idx] + acc[i][j][r];
                C[idx] = v;
                sum += v; ssq += v*v;
            }
            sum += __shfl_xor(sum, 1); ssq += __shfl_xor(ssq, 1);
            sum += __shfl_xor(sum, 2); ssq += __shfl_xor(ssq, 2);
            sum += __shfl_xor(sum, 4); ssq += __shfl_xor(ssq, 4);
            sum += __shfl_xor(sum, 8); ssq += __shfl_xor(ssq, 8);
            if (l16 == 0) stp[(size_t)slot*BLP_ + row] = make_float2(sum, ssq);
        }
    }
}

// ---- fused conv(4)+silu + x_proj MFMA + dt_proj + scan phase1 ----
__global__ __launch_bounds__(256) void conv_xproj_kernel(
    const ushort_t* __restrict__ xz, const float* __restrict__ cw,
    const float* __restrict__ cb, const ushort_t* __restrict__ XWb,
    const float* __restrict__ DTW, const float* __restrict__ DTB,
    const float* __restrict__ Alog,
    ushort_t* __restrict__ u_bf, float* __restrict__ bn,
    float* __restrict__ cn, ushort_t* __restrict__ dtn,
    float* __restrict__ send, float* __restrict__ aprod)
{
    __shared__ ushort_t xs[19][520];
    __shared__ ushort_t us[16][520];
    __shared__ float ps[4*16*48];
    __shared__ float dtr_s[16][16];
    const int c = blockIdx.x, b = blockIdx.y;
    const int l0 = c * 16;
    const int tid = threadIdx.x;
    const int lane = tid & 63, w = tid >> 6;
    const int qd = lane >> 4, l16 = lane & 15;
    for (int f = tid; f < 19*64; f += 256) {
        int row = f >> 6, c8 = (f & 63)*8;
        int l = l0 - 3 + row;
        uint4 v = {0u, 0u, 0u, 0u};
        if (l >= 0)
            v = *(const uint4*)(xz + (size_t)(b*L_ + l)*1024 + c8);
        *(uint4*)&xs[row][c8] = v;
    }
    __syncthreads();
    #pragma unroll
    for (int q = 0; q < 2; q++) {
        int ch = tid + q*256;
        float4 wv = *(const float4*)(cw + ch*4);
        float bias = cb[ch];
        float x0 = bf2f(xs[0][ch]);
        float x1 = bf2f(xs[1][ch]);
        float x2 = bf2f(xs[2][ch]);
        #pragma unroll
        for (int j = 0; j < 16; j++) {
            float x3 = bf2f(xs[3 + j][ch]);
            float v = fmaf(x0, wv.x, fmaf(x1, wv.y, fmaf(x2, wv.z, fmaf(x3, wv.w, bias))));
            us[j][ch] = f2bf(siluf(v));
            x0 = x1; x1 = x2; x2 = x3;
        }
    }
    __syncthreads();
    for (int f = tid; f < 16*64; f += 256) {
        int row = f >> 6, c8 = (f & 63)*8;
        *(uint4*)(u_bf + (size_t)(b*L_ + l0 + row)*512 + c8) =
            *(const uint4*)&us[row][c8];
    }
    f32x4 acc[3] = {};
    #pragma unroll
    for (int step = 0; step < 4; step++) {
        int k = w*128 + step*32 + qd*8;
        bf16x8 af = *(const bf16x8*)&us[l16][k];
        #pragma unroll
        for (int j = 0; j < 3; j++) {
            bf16x8 bf = *(const bf16x8*)(XWb + (size_t)(j*16 + l16)*512 + k);
            acc[j] = __builtin_amdgcn_mfma_f32_16x16x32_bf16(af, bf, acc[j], 0, 0, 0);
        }
    }
    #pragma unroll
    for (int j = 0; j < 3; j++) {
        #pragma unroll
        for (int r = 0; r < 4; r++)
            ps[(w*16 + qd*4 + r)*48 + j*16 + l16] = acc[j][r];
    }
    __syncthreads();
    #pragma unroll
    for (int e = tid; e < 768; e += 256)
        ps[e] = ps[e] + ps[768 + e] + ps[1536 + e] + ps[2304 + e];
    __syncthreads();
    {
        int row = tid >> 4, n = tid & 15;
        dtr_s[row][n] = ps[row*48 + n];
        size_t base = ((size_t)(b*L_) + l0 + row)*DS_ + n;
        bn[base] = ps[row*48 + 16 + n];
        cn[base] = ps[row*48 + 32 + n];
    }
    __syncthreads();
    #pragma unroll
    for (int q = 0; q < 2; q++) {
        int d = tid + q*256;
        float wreg[16];
        const float4* wp = (const float4*)(DTW + (size_t)d*16);
        #pragma unroll
        for (int k4 = 0; k4 < 4; k4++) {
            float4 v = wp[k4];
            wreg[4*k4+0] = v.x; wreg[4*k4+1] = v.y;
            wreg[4*k4+2] = v.z; wreg[4*k4+3] = v.w;
        }
        float bias = DTB[d];
        float dtv[16];
        #pragma unroll
        for (int r = 0; r < 16; r++) {
            float a = bias;
            #pragma unroll
            for (int k = 0; k < 16; k++) a = fmaf(dtr_s[r][k], wreg[k], a);
            float dt = a > 20.f ? a : log1pf(__expf(a));
            ushort_t dtb16 = f2bf(dt);
            dtn[((size_t)(b*L_) + l0 + r)*DI_ + d] = dtb16;
            dtv[r] = bf2f(dtb16);
        }
        float Ac[DS_], s[DS_], ap[DS_];
        const float* ar = Alog + (size_t)d*DS_;
        #pragma unroll
        for (int n = 0; n < DS_; n++) { Ac[n] = -__expf(ar[n]); s[n] = 0.f; ap[n] = 1.f; }
        #pragma unroll
        for (int l = 0; l < 16; l++) {
            float dt = dtv[l];
            float u  = bf2f(us[l][d]);
            float dtu = dt*u;
            #pragma unroll
            for (int n = 0; n < DS_; n++) {
                float e = __expf(dt*Ac[n]);
                s[n] = fmaf(e, s[n], dtu*ps[l*48 + 16 + n]);
                ap[n] *= e;
            }
        }
        size_t base = (((size_t)c*B_ + b)*DI_ + d)*DS_;
        #pragma unroll
        for (int n4 = 0; n4 < 4; n4++) {
            *(float4*)(send  + base + 4*n4) = *(float4*)&s[4*n4];
            *(float4*)(aprod + base + 4*n4) = *(float4*)&ap[4*n4];
        }
    }
}

// ---- cooperative scan: phase2 (first 128 blocks) + grid.sync + phase3 ----
// grid (NC_, DI_/128, B_) = 1000 blocks x 128 threads, co-resident (~4 blk/CU).
__global__ __launch_bounds__(128) void scan_p23(
    const ushort_t* __restrict__ dtn, const ushort_t* __restrict__ u_bf,
    const float* __restrict__ bn, const float* __restrict__ cn,
    const float* __restrict__ Alog, const float* __restrict__ Dv,
    float* __restrict__ send, const float* __restrict__ aprod,
    const ushort_t* __restrict__ xz, ushort_t* __restrict__ ysb)
{
    cg::grid_group grid = cg::this_grid();
    // ---- phase2: 16384 chains on the first 128 blocks (1 chain/thread) ----
    const int fid = (blockIdx.z*gridDim.y + blockIdx.y)*gridDim.x + blockIdx.x;
    if (fid < 128) {
        int t = fid*128 + threadIdx.x;
        float s = 0.f;
        for (int c = 0; c < NC_; c++) {
            size_t idx = (size_t)c*(B_*DI_*DS_) + t;
            float tmp = send[idx];
            send[idx] = s;
            s = fmaf(aprod[idx], s, tmp);
        }
        __threadfence();   // device-scope release: flush send past per-XCD L2
    }
    grid.sync();
    // ---- phase3 (unchanged body) ----
    __shared__ float b_sh[CL_*DS_];
    __shared__ float c_sh[CL_*DS_];
    const int c = blockIdx.x, qy = blockIdx.y, b = blockIdx.z;
    const int tid = threadIdx.x;
    const int d = qy*128 + tid;
    const int l0 = c*CL_;
    for (int f = tid; f < CL_*DS_; f += 128) {
        size_t src = ((size_t)(b*L_) + l0)*DS_ + f;
        b_sh[f] = bn[src];
        c_sh[f] = cn[src];
    }
    float Ac[DS_], s[DS_];
    const float* ar = Alog + (size_t)d*DS_;
    #pragma unroll
    for (int n = 0; n < DS_; n++) Ac[n] = -__expf(ar[n]);
    {
        size_t base = (((size_t)c*B_ + b)*DI_ + d)*DS_;
        #pragma unroll
        for (int n4 = 0; n4 < 4; n4++)
            *(float4*)&s[4*n4] = *(const float4*)(send + base + 4*n4);
    }
    const float Dd = Dv[d];
    __syncthreads();
    const ushort_t* dtp = dtn  + ((size_t)(b*L_ + l0))*DI_ + d;
    const ushort_t* up  = u_bf + ((size_t)(b*L_ + l0))*DI_ + d;
    const ushort_t* zp  = xz   + ((size_t)(b*L_ + l0))*1024 + 512 + d;
    ushort_t*       yo  = ysb  + ((size_t)(b*L_ + l0))*DI_ + d;
    for (int l = 0; l < CL_; l++) {
        float dt = bf2f(dtp[(size_t)l*DI_]);
        float u  = bf2f(up[(size_t)l*DI_]);
        float z  = bf2f(zp[(size_t)l*1024]);
        float dtu = dt*u;
        float bv[DS_], cv[DS_];
        #pragma unroll
        for (int n4 = 0; n4 < 4; n4++) {
            *(float4*)&bv[4*n4] = *(const float4*)&b_sh[l*DS_ + 4*n4];
            *(float4*)&cv[4*n4] = *(const float4*)&c_sh[l*DS_ + 4*n4];
        }
        float y = u*Dd;
        #pragma unroll
        for (int n = 0; n < DS_; n++) {
            float e = __expf(dt*Ac[n]);
            s[n] = fmaf(e, s[n], dtu*bv[n]);
            y = fmaf(s[n], cv[n], y);
        }
        yo[(size_t)l*DI_] = f2bf(y * siluf(z));
    }
}

// ---------------- final LN + head dot ----------------
__global__ __launch_bounds__(256) void final_kernel(
    const float* __restrict__ h, const float* __restrict__ fw,
    const float* __restrict__ fb, const float* __restrict__ hw,
    const float* __restrict__ hb, float* __restrict__ out)
{
    __shared__ float sm[4];
    int row = blockIdx.x, tid = threadIdx.x;
    float v = h[(size_t)row*DM_ + tid];
    float s = v;
    #pragma unroll
    for (int o = 32; o > 0; o >>= 1) s += __shfl_down(s, o);
    if ((tid & 63) == 0) sm[tid >> 6] = s;
    __syncthreads();
    float mu = (sm[0]+sm[1]+sm[2]+sm[3]) * (1.f/DM_);
    __syncthreads();
    float dv = v - mu;
    float q = dv*dv;
    #pragma unroll
    for (int o = 32; o > 0; o >>= 1) q += __shfl_down(q, o);
    if ((tid & 63) == 0) sm[tid >> 6] = q;
    __syncthreads();
    float var = (sm[0]+sm[1]+sm[2]+sm[3]) * (1.f/DM_);
    float nv = dv * rsqrtf(var + 1e-5f) * fw[tid] + fb[tid];
    float p = nv * hw[tid];
    __syncthreads();
    #pragma unroll
    for (int o = 32; o > 0; o >>= 1) p += __shfl_down(p, o);
    if ((tid & 63) == 0) sm[tid >> 6] = p;
    __syncthreads();
    if (tid == 0) out[row] = sm[0]+sm[1]+sm[2]+sm[3] + hb[0];
}

extern "C" void kernel_launch(void* const* d_in, const int* in_sizes, int n_in,
                              void* d_out, int out_size, void* d_ws, size_t ws_size,
                              hipStream_t stream)
{
    const float* x    = (const float*)d_in[0];
    const float* biw  = (const float*)d_in[1];
    const float* bib  = (const float*)d_in[2];
    const float* ge   = (const float*)d_in[3];
    const float* me   = (const float*)d_in[4];
    const float* lnw  = (const float*)d_in[5];
    const float* lnb  = (const float*)d_in[6];
    const float* ipw  = (const float*)d_in[7];
    const float* cw   = (const float*)d_in[8];
    const float* cb   = (const float*)d_in[9];
    const float* xpw  = (const float*)d_in[10];
    const float* dtw  = (const float*)d_in[11];
    const float* dtb  = (const float*)d_in[12];
    const float* alog = (const float*)d_in[13];
    const float* Dv   = (const float*)d_in[14];
    const float* opw  = (const float*)d_in[15];
    const float* fw   = (const float*)d_in[16];
    const float* fb   = (const float*)d_in[17];
    const float* hw   = (const float*)d_in[18];
    const float* hb   = (const float*)d_in[19];
    float* out = (float*)d_out;

    // workspace layout (float units; 16B-aligned); ~45 MB
    float* ws  = (float*)d_ws;
    float* h      = ws;                                  // 1,048,576 f
    float2* stats = (float2*)(h + (size_t)BLP_*DM_);     // 4*BLP_ float2
    float* bn     = (float*)(stats + 4*BLP_);            // 64,000 f (b,l,n)
    float* cn     = bn + (size_t)B_*L_*DS_;              // 64,000 f
    float* send   = cn + (size_t)B_*L_*DS_;              // 2,048,000 f
    float* aprod  = send + (size_t)B_*DI_*DS_*NC_;       // 2,048,000 f
    ushort_t* xz_bf = (ushort_t*)(aprod + (size_t)B_*DI_*DS_*NC_); // BLP_*1024 us
    ushort_t* u_bf  = xz_bf + (size_t)BLP_*1024;         // BLP_*DI_ us
    ushort_t* ysbb  = u_bf + (size_t)BLP_*DI_;           // BLP_*DI_ us
    ushort_t* dtn   = ysbb + (size_t)BLP_*DI_;           // B_*L_*DI_ us (bf16)
    ushort_t* ipwb  = dtn + (size_t)B_*L_*DI_;           // NL_*1024*DM_ us
    ushort_t* opwb  = ipwb + (size_t)NL_*1024*DM_;       // NL_*DM_*DI_ us
    ushort_t* xpwb  = opwb + (size_t)NL_*DM_*DI_;        // NL_*48*512 us

    // convert all weights to bf16 in one launch
    const int N0 = NL_*1024*DM_/4, N1 = NL_*DM_*DI_/4, N2 = NL_*48*512/4;
    f2bf3_kernel<<<(N0+N1+N2 + 255)/256, 256, 0, stream>>>(
        ipw, opw, xpw, ipwb, opwb, xpwb, N0, N1, N2);

    embed_kernel<<<BL_, 256, 0, stream>>>(x, biw, bib, ge, me, h, stats);
    for (int i = 0; i < NL_; i++) {
        gemm_ln_mfma<<<dim3(BLP_/128, 1024/128), 256, 0, stream>>>(
            h, stats, lnw + i*DM_, lnb + i*DM_,
            ipwb + (size_t)i*1024*DM_, xz_bf, 1024);
        conv_xproj_kernel<<<dim3(NC_, B_), 256, 0, stream>>>(
            xz_bf, cw + i*DI_*4, cb + i*DI_, xpwb + (size_t)i*48*512,
            dtw + (size_t)i*DI_*16, dtb + i*DI_, alog + (size_t)i*DI_*DS_,
            u_bf, bn, cn, dtn, send, aprod);
        {
            const ushort_t* dtn_c = dtn; const ushort_t* u_c = u_bf;
            const float* bn_c = bn; const float* cn_c = cn;
            const float* alog_l = alog + (size_t)i*DI_*DS_;
            const float* dv_l = Dv + i*DI_;
            float* send_m = send; const float* ap_c = aprod;
            const ushort_t* xz_c = xz_bf; ushort_t* ys_m = ysbb;
            void* args[] = {(void*)&dtn_c, (void*)&u_c, (void*)&bn_c, (void*)&cn_c,
                            (void*)&alog_l, (void*)&dv_l, (void*)&send_m,
                            (void*)&ap_c, (void*)&xz_c, (void*)&ys_m};
            hipLaunchCooperativeKernel((void*)scan_p23,
                dim3(NC_, DI_/128, B_), dim3(128), args, 0, stream);
        }
        gemm_out_mfma<<<dim3(BLP_/128, DM_/128), 256, 0, stream>>>(
            ysbb, opwb + (size_t)i*DM_*DI_, h, DM_, DI_, stats);
    }
    final_kernel<<<BL_, 256, 0, stream>>>(h, fw, fb, hw, hb, out);
}

// Round 17
// 477.223 us; speedup vs baseline: 1.7354x; 1.7354x over previous
//
#include <hip/hip_runtime.h>
#include <math.h>

#define B_  2
#define L_  2000
#define DM_ 256
#define DI_ 512
#define DS_ 16
#define NL_ 4
#define BL_ (B_*L_)     // 4000
#define BLP_ 4096       // rows padded to multiple of 64
#define NC_ 125         // scan chunks == conv strips (CL=16)
#define CL_ 16          // chunk length == conv_xproj strip

typedef unsigned short ushort_t;
typedef __attribute__((ext_vector_type(8))) short bf16x8;
typedef __attribute__((ext_vector_type(4))) float f32x4;

__device__ __forceinline__ float siluf(float x) {
    return x / (1.f + __expf(-x));
}

__device__ __forceinline__ ushort_t f2bf(float x) {
    unsigned int u = __float_as_uint(x);
    unsigned int r = (u + 0x7FFFu + ((u >> 16) & 1u)) >> 16;
    return (ushort_t)r;
}

__device__ __forceinline__ float bf2f(ushort_t v) {
    return __uint_as_float(((unsigned int)v) << 16);
}

// ---------------- fp32 -> bf16 conversion, 3 segments in one launch ----------------
__global__ __launch_bounds__(256) void f2bf3_kernel(
    const float* __restrict__ s0, const float* __restrict__ s1,
    const float* __restrict__ s2, ushort_t* __restrict__ d0,
    ushort_t* __restrict__ d1, ushort_t* __restrict__ d2,
    int N0, int N1, int N2)
{
    int i = blockIdx.x*256 + threadIdx.x;
    const float* s; ushort_t* d; int j;
    if (i < N0)           { s = s0; d = d0; j = i; }
    else if (i < N0+N1)   { s = s1; d = d1; j = i - N0; }
    else if (i < N0+N1+N2){ s = s2; d = d2; j = i - N0 - N1; }
    else return;
    float4 v = *(const float4*)(s + 4*j);
    ushort_t o[4] = {f2bf(v.x), f2bf(v.y), f2bf(v.z), f2bf(v.w)};
    *(ushort2*)(d + 4*j)     = *(ushort2*)&o[0];
    *(ushort2*)(d + 4*j + 2) = *(ushort2*)&o[2];
}

// ---------------- embed: h = x*biw + bib + ge + me; emit row LN stats ----------------
__global__ __launch_bounds__(256) void embed_kernel(
    const float* __restrict__ x, const float* __restrict__ biw,
    const float* __restrict__ bib, const float* __restrict__ ge,
    const float* __restrict__ me, float* __restrict__ h,
    float2* __restrict__ stats)
{
    __shared__ float sm[8];
    int bl = blockIdx.x, d = threadIdx.x;
    int l = bl % L_;
    float v = x[bl]*biw[d] + bib[d] + ge[(size_t)l*DM_ + d] + me[d];
    h[(size_t)bl*DM_ + d] = v;
    float s = v, q = v*v;
    #pragma unroll
    for (int o = 32; o > 0; o >>= 1) {
        s += __shfl_down(s, o);
        q += __shfl_down(q, o);
    }
    if ((d & 63) == 0) { sm[d >> 6] = s; sm[4 + (d >> 6)] = q; }
    __syncthreads();
    if (d == 0) {
        stats[bl] = make_float2(sm[0]+sm[1]+sm[2]+sm[3], sm[4]+sm[5]+sm[6]+sm[7]);
        stats[BLP_ + bl]   = make_float2(0.f, 0.f);
        stats[2*BLP_ + bl] = make_float2(0.f, 0.f);
        stats[3*BLP_ + bl] = make_float2(0.f, 0.f);
    }
}

// ---------------- fused LN + in_proj MFMA GEMM ----------------
__global__ __launch_bounds__(256) void gemm_ln_mfma(
    const float* __restrict__ H, const float2* __restrict__ stats,
    const float* __restrict__ lnw, const float* __restrict__ lnb,
    const ushort_t* __restrict__ W, ushort_t* __restrict__ C, int ldc)
{
    __shared__ ushort_t a_s[128*64];
    __shared__ ushort_t b_s[128*64];
    const int r0 = blockIdx.x*128, c0 = blockIdx.y*128;
    const int tid = threadIdx.x;
    const int lane = tid & 63, w = tid >> 6;
    const int wm = (w & 1)*64, wn = (w >> 1)*64;
    const int qd = lane >> 4, l16 = lane & 15;
    f32x4 acc[4][4] = {};
    for (int kc = 0; kc < DM_; kc += 64) {
        #pragma unroll
        for (int q = 0; q < 4; q++) {
            int ch = tid + 256*q;              // 0..1023
            int row = ch >> 3, col8 = (ch & 7)*8;
            int grow = r0 + row;
            float2 t0 = stats[grow], t1 = stats[BLP_ + grow];
            float2 t2 = stats[2*BLP_ + grow], t3 = stats[3*BLP_ + grow];
            float sum = t0.x + t1.x + t2.x + t3.x;
            float ssq = t0.y + t1.y + t2.y + t3.y;
            float mu  = sum * (1.f/DM_);
            float inv = rsqrtf(fmaxf(ssq*(1.f/DM_) - mu*mu, 0.f) + 1e-5f);
            const float* hp = H + (size_t)grow*DM_ + kc + col8;
            float4 h0 = *(const float4*)hp, h1 = *(const float4*)(hp + 4);
            const float* wp = lnw + kc + col8;
            const float* bp = lnb + kc + col8;
            float4 w0 = *(const float4*)wp, w1 = *(const float4*)(wp + 4);
            float4 b0 = *(const float4*)bp, b1 = *(const float4*)(bp + 4);
            __align__(16) ushort_t o[8];
            o[0] = f2bf((h0.x - mu)*inv*w0.x + b0.x);
            o[1] = f2bf((h0.y - mu)*inv*w0.y + b0.y);
            o[2] = f2bf((h0.z - mu)*inv*w0.z + b0.z);
            o[3] = f2bf((h0.w - mu)*inv*w0.w + b0.w);
            o[4] = f2bf((h1.x - mu)*inv*w1.x + b1.x);
            o[5] = f2bf((h1.y - mu)*inv*w1.y + b1.y);
            o[6] = f2bf((h1.z - mu)*inv*w1.z + b1.z);
            o[7] = f2bf((h1.w - mu)*inv*w1.w + b1.w);
            *(uint4*)&a_s[row*64 + col8] = *(const uint4*)o;
            *(bf16x8*)&b_s[row*64 + col8] =
                *(const bf16x8*)(W + (size_t)(c0 + row)*DM_ + kc + col8);
        }
        __syncthreads();
        #pragma unroll
        for (int ks = 0; ks < 2; ks++) {
            bf16x8 af[4], bf[4];
            #pragma unroll
            for (int i = 0; i < 4; i++)
                af[i] = *(const bf16x8*)&a_s[(wm + i*16 + l16)*64 + ks*32 + qd*8];
            #pragma unroll
            for (int j = 0; j < 4; j++)
                bf[j] = *(const bf16x8*)&b_s[(wn + j*16 + l16)*64 + ks*32 + qd*8];
            #pragma unroll
            for (int i = 0; i < 4; i++) {
                #pragma unroll
                for (int j = 0; j < 4; j++)
                    acc[i][j] = __builtin_amdgcn_mfma_f32_16x16x32_bf16(
                        af[i], bf[j], acc[i][j], 0, 0, 0);
            }
        }
        __syncthreads();
    }
    #pragma unroll
    for (int i = 0; i < 4; i++) {
        #pragma unroll
        for (int j = 0; j < 4; j++) {
            #pragma unroll
            for (int r = 0; r < 4; r++) {
                int row = r0 + wm + i*16 + qd*4 + r;
                int col = c0 + wn + j*16 + l16;
                C[(size_t)row*ldc + col] = f2bf(acc[i][j][r]);
            }
        }
    }
}

// ---------------- out_proj MFMA GEMM with h += and LN-stats epilogue ----------------
__global__ __launch_bounds__(256) void gemm_out_mfma(
    const ushort_t* __restrict__ A, const ushort_t* __restrict__ W,
    float* __restrict__ C, int ldc, int K, float2* __restrict__ stp)
{
    __shared__ ushort_t a_s[128*64];
    __shared__ ushort_t b_s[128*64];
    const int r0 = blockIdx.x*128, c0 = blockIdx.y*128;
    const int tid = threadIdx.x;
    const int lane = tid & 63, w = tid >> 6;
    const int wm = (w & 1)*64, wn = (w >> 1)*64;
    const int qd = lane >> 4, l16 = lane & 15;
    f32x4 acc[4][4] = {};
    for (int kc = 0; kc < K; kc += 64) {
        #pragma unroll
        for (int q = 0; q < 4; q++) {
            int ch = tid + 256*q;
            int row = ch >> 3, col8 = (ch & 7)*8;
            *(bf16x8*)&a_s[row*64 + col8] =
                *(const bf16x8*)(A + (size_t)(r0 + row)*K + kc + col8);
            *(bf16x8*)&b_s[row*64 + col8] =
                *(const bf16x8*)(W + (size_t)(c0 + row)*K + kc + col8);
        }
        __syncthreads();
        #pragma unroll
        for (int ks = 0; ks < 2; ks++) {
            bf16x8 af[4], bf[4];
            #pragma unroll
            for (int i = 0; i < 4; i++)
                af[i] = *(const bf16x8*)&a_s[(wm + i*16 + l16)*64 + ks*32 + qd*8];
            #pragma unroll
            for (int j = 0; j < 4; j++)
                bf[j] = *(const bf16x8*)&b_s[(wn + j*16 + l16)*64 + ks*32 + qd*8];
            #pragma unroll
            for (int i = 0; i < 4; i++) {
                #pragma unroll
                for (int j = 0; j < 4; j++)
                    acc[i][j] = __builtin_amdgcn_mfma_f32_16x16x32_bf16(
                        af[i], bf[j], acc[i][j], 0, 0, 0);
            }
        }
        __syncthreads();
    }
    const int slot = blockIdx.y*2 + (w >> 1);
    #pragma unroll
    for (int i = 0; i < 4; i++) {
        #pragma unroll
        for (int r = 0; r < 4; r++) {
            int row = r0 + wm + i*16 + qd*4 + r;
            float sum = 0.f, ssq = 0.f;
            #pragma unroll
            for (int j = 0; j < 4; j++) {
                int col = c0 + wn + j*16 + l16;
                size_t idx = (size_t)row*ldc + col;
                float v = C[idx] + acc[i][j][r];
                C[idx] = v;
                sum += v; ssq += v*v;
            }
            sum += __shfl_xor(sum, 1); ssq += __shfl_xor(ssq, 1);
            sum += __shfl_xor(sum, 2); ssq += __shfl_xor(ssq, 2);
            sum += __shfl_xor(sum, 4); ssq += __shfl_xor(ssq, 4);
            sum += __shfl_xor(sum, 8); ssq += __shfl_xor(ssq, 8);
            if (l16 == 0) stp[(size_t)slot*BLP_ + row] = make_float2(sum, ssq);
        }
    }
}

// ---- fused conv(4)+silu + x_proj MFMA + dt_proj + scan phase1 ----
__global__ __launch_bounds__(256) void conv_xproj_kernel(
    const ushort_t* __restrict__ xz, const float* __restrict__ cw,
    const float* __restrict__ cb, const ushort_t* __restrict__ XWb,
    const float* __restrict__ DTW, const float* __restrict__ DTB,
    const float* __restrict__ Alog,
    ushort_t* __restrict__ u_bf, float* __restrict__ bn,
    float* __restrict__ cn, ushort_t* __restrict__ dtn,
    float* __restrict__ send, float* __restrict__ aprod)
{
    __shared__ ushort_t xs[19][520];
    __shared__ ushort_t us[16][520];
    __shared__ float ps[4*16*48];
    __shared__ float dtr_s[16][16];
    const int c = blockIdx.x, b = blockIdx.y;
    const int l0 = c * 16;
    const int tid = threadIdx.x;
    const int lane = tid & 63, w = tid >> 6;
    const int qd = lane >> 4, l16 = lane & 15;
    for (int f = tid; f < 19*64; f += 256) {
        int row = f >> 6, c8 = (f & 63)*8;
        int l = l0 - 3 + row;
        uint4 v = {0u, 0u, 0u, 0u};
        if (l >= 0)
            v = *(const uint4*)(xz + (size_t)(b*L_ + l)*1024 + c8);
        *(uint4*)&xs[row][c8] = v;
    }
    __syncthreads();
    #pragma unroll
    for (int q = 0; q < 2; q++) {
        int ch = tid + q*256;
        float4 wv = *(const float4*)(cw + ch*4);
        float bias = cb[ch];
        float x0 = bf2f(xs[0][ch]);
        float x1 = bf2f(xs[1][ch]);
        float x2 = bf2f(xs[2][ch]);
        #pragma unroll
        for (int j = 0; j < 16; j++) {
            float x3 = bf2f(xs[3 + j][ch]);
            float v = fmaf(x0, wv.x, fmaf(x1, wv.y, fmaf(x2, wv.z, fmaf(x3, wv.w, bias))));
            us[j][ch] = f2bf(siluf(v));
            x0 = x1; x1 = x2; x2 = x3;
        }
    }
    __syncthreads();
    for (int f = tid; f < 16*64; f += 256) {
        int row = f >> 6, c8 = (f & 63)*8;
        *(uint4*)(u_bf + (size_t)(b*L_ + l0 + row)*512 + c8) =
            *(const uint4*)&us[row][c8];
    }
    f32x4 acc[3] = {};
    #pragma unroll
    for (int step = 0; step < 4; step++) {
        int k = w*128 + step*32 + qd*8;
        bf16x8 af = *(const bf16x8*)&us[l16][k];
        #pragma unroll
        for (int j = 0; j < 3; j++) {
            bf16x8 bf = *(const bf16x8*)(XWb + (size_t)(j*16 + l16)*512 + k);
            acc[j] = __builtin_amdgcn_mfma_f32_16x16x32_bf16(af, bf, acc[j], 0, 0, 0);
        }
    }
    #pragma unroll
    for (int j = 0; j < 3; j++) {
        #pragma unroll
        for (int r = 0; r < 4; r++)
            ps[(w*16 + qd*4 + r)*48 + j*16 + l16] = acc[j][r];
    }
    __syncthreads();
    #pragma unroll
    for (int e = tid; e < 768; e += 256)
        ps[e] = ps[e] + ps[768 + e] + ps[1536 + e] + ps[2304 + e];
    __syncthreads();
    {
        int row = tid >> 4, n = tid & 15;
        dtr_s[row][n] = ps[row*48 + n];
        size_t base = ((size_t)(b*L_) + l0 + row)*DS_ + n;
        bn[base] = ps[row*48 + 16 + n];
        cn[base] = ps[row*48 + 32 + n];
    }
    __syncthreads();
    #pragma unroll
    for (int q = 0; q < 2; q++) {
        int d = tid + q*256;
        float wreg[16];
        const float4* wp = (const float4*)(DTW + (size_t)d*16);
        #pragma unroll
        for (int k4 = 0; k4 < 4; k4++) {
            float4 v = wp[k4];
            wreg[4*k4+0] = v.x; wreg[4*k4+1] = v.y;
            wreg[4*k4+2] = v.z; wreg[4*k4+3] = v.w;
        }
        float bias = DTB[d];
        float dtv[16];
        #pragma unroll
        for (int r = 0; r < 16; r++) {
            float a = bias;
            #pragma unroll
            for (int k = 0; k < 16; k++) a = fmaf(dtr_s[r][k], wreg[k], a);
            float dt = a > 20.f ? a : log1pf(__expf(a));
            ushort_t dtb16 = f2bf(dt);
            dtn[((size_t)(b*L_) + l0 + r)*DI_ + d] = dtb16;
            dtv[r] = bf2f(dtb16);              // phase1 uses same value as phase3
        }
        float Ac[DS_], s[DS_], ap[DS_];
        const float* ar = Alog + (size_t)d*DS_;
        #pragma unroll
        for (int n = 0; n < DS_; n++) { Ac[n] = -__expf(ar[n]); s[n] = 0.f; ap[n] = 1.f; }
        #pragma unroll
        for (int l = 0; l < 16; l++) {
            float dt = dtv[l];
            float u  = bf2f(us[l][d]);
            float dtu = dt*u;
            #pragma unroll
            for (int n = 0; n < DS_; n++) {
                float e = __expf(dt*Ac[n]);
                s[n] = fmaf(e, s[n], dtu*ps[l*48 + 16 + n]);   // broadcast read
                ap[n] *= e;
            }
        }
        size_t base = (((size_t)c*B_ + b)*DI_ + d)*DS_;
        #pragma unroll
        for (int n4 = 0; n4 < 4; n4++) {
            *(float4*)(send  + base + 4*n4) = *(float4*)&s[4*n4];
            *(float4*)(aprod + base + 4*n4) = *(float4*)&ap[4*n4];
        }
    }
}

__global__ __launch_bounds__(256) void scan_phase2(
    float* __restrict__ send, const float* __restrict__ aprod)
{
    int t = blockIdx.x*256 + threadIdx.x;   // B_*DI_*DS_ = 16384 threads
    float s = 0.f;
    for (int c = 0; c < NC_; c++) {
        size_t idx = (size_t)c*(B_*DI_*DS_) + t;         // coalesced per c
        float tmp = send[idx];
        send[idx] = s;
        s = fmaf(aprod[idx], s, tmp);
    }
}

// Phase 3: re-run chunk with incoming state; fuse (y + u*D)*silu(z) -> bf16.
__global__ __launch_bounds__(128) void scan_phase3(
    const ushort_t* __restrict__ dtn, const ushort_t* __restrict__ u_bf,
    const float* __restrict__ bn, const float* __restrict__ cn,
    const float* __restrict__ Alog, const float* __restrict__ Dv,
    const float* __restrict__ sin_, const ushort_t* __restrict__ xz,
    ushort_t* __restrict__ ysb)
{
    __shared__ float b_sh[CL_*DS_];
    __shared__ float c_sh[CL_*DS_];
    const int c = blockIdx.x, qy = blockIdx.y, b = blockIdx.z;
    const int tid = threadIdx.x;
    const int d = qy*128 + tid;
    const int l0 = c*CL_;
    for (int f = tid; f < CL_*DS_; f += 128) {
        size_t src = ((size_t)(b*L_) + l0)*DS_ + f;
        b_sh[f] = bn[src];
        c_sh[f] = cn[src];
    }
    float Ac[DS_], s[DS_];
    const float* ar = Alog + (size_t)d*DS_;
    #pragma unroll
    for (int n = 0; n < DS_; n++) Ac[n] = -__expf(ar[n]);
    {
        size_t base = (((size_t)c*B_ + b)*DI_ + d)*DS_;
        #pragma unroll
        for (int n4 = 0; n4 < 4; n4++)
            *(float4*)&s[4*n4] = *(const float4*)(sin_ + base + 4*n4);
    }
    const float Dd = Dv[d];
    __syncthreads();
    const ushort_t* dtp = dtn  + ((size_t)(b*L_ + l0))*DI_ + d;
    const ushort_t* up  = u_bf + ((size_t)(b*L_ + l0))*DI_ + d;
    const ushort_t* zp  = xz   + ((size_t)(b*L_ + l0))*1024 + 512 + d;
    ushort_t*       yo  = ysb  + ((size_t)(b*L_ + l0))*DI_ + d;
    for (int l = 0; l < CL_; l++) {
        float dt = bf2f(dtp[(size_t)l*DI_]);
        float u  = bf2f(up[(size_t)l*DI_]);
        float z  = bf2f(zp[(size_t)l*1024]);
        float dtu = dt*u;
        float bv[DS_], cv[DS_];
        #pragma unroll
        for (int n4 = 0; n4 < 4; n4++) {
            *(float4*)&bv[4*n4] = *(const float4*)&b_sh[l*DS_ + 4*n4];
            *(float4*)&cv[4*n4] = *(const float4*)&c_sh[l*DS_ + 4*n4];
        }
        float y = u*Dd;
        #pragma unroll
        for (int n = 0; n < DS_; n++) {
            float e = __expf(dt*Ac[n]);
            s[n] = fmaf(e, s[n], dtu*bv[n]);
            y = fmaf(s[n], cv[n], y);
        }
        yo[(size_t)l*DI_] = f2bf(y * siluf(z));
    }
}

// ---------------- final LN + head dot ----------------
__global__ __launch_bounds__(256) void final_kernel(
    const float* __restrict__ h, const float* __restrict__ fw,
    const float* __restrict__ fb, const float* __restrict__ hw,
    const float* __restrict__ hb, float* __restrict__ out)
{
    __shared__ float sm[4];
    int row = blockIdx.x, tid = threadIdx.x;
    float v = h[(size_t)row*DM_ + tid];
    float s = v;
    #pragma unroll
    for (int o = 32; o > 0; o >>= 1) s += __shfl_down(s, o);
    if ((tid & 63) == 0) sm[tid >> 6] = s;
    __syncthreads();
    float mu = (sm[0]+sm[1]+sm[2]+sm[3]) * (1.f/DM_);
    __syncthreads();
    float dv = v - mu;
    float q = dv*dv;
    #pragma unroll
    for (int o = 32; o > 0; o >>= 1) q += __shfl_down(q, o);
    if ((tid & 63) == 0) sm[tid >> 6] = q;
    __syncthreads();
    float var = (sm[0]+sm[1]+sm[2]+sm[3]) * (1.f/DM_);
    float nv = dv * rsqrtf(var + 1e-5f) * fw[tid] + fb[tid];
    float p = nv * hw[tid];
    __syncthreads();
    #pragma unroll
    for (int o = 32; o > 0; o >>= 1) p += __shfl_down(p, o);
    if ((tid & 63) == 0) sm[tid >> 6] = p;
    __syncthreads();
    if (tid == 0) out[row] = sm[0]+sm[1]+sm[2]+sm[3] + hb[0];
}

extern "C" void kernel_launch(void* const* d_in, const int* in_sizes, int n_in,
                              void* d_out, int out_size, void* d_ws, size_t ws_size,
                              hipStream_t stream)
{
    const float* x    = (const float*)d_in[0];
    const float* biw  = (const float*)d_in[1];
    const float* bib  = (const float*)d_in[2];
    const float* ge   = (const float*)d_in[3];
    const float* me   = (const float*)d_in[4];
    const float* lnw  = (const float*)d_in[5];
    const float* lnb  = (const float*)d_in[6];
    const float* ipw  = (const float*)d_in[7];
    const float* cw   = (const float*)d_in[8];
    const float* cb   = (const float*)d_in[9];
    const float* xpw  = (const float*)d_in[10];
    const float* dtw  = (const float*)d_in[11];
    const float* dtb  = (const float*)d_in[12];
    const float* alog = (const float*)d_in[13];
    const float* Dv   = (const float*)d_in[14];
    const float* opw  = (const float*)d_in[15];
    const float* fw   = (const float*)d_in[16];
    const float* fb   = (const float*)d_in[17];
    const float* hw   = (const float*)d_in[18];
    const float* hb   = (const float*)d_in[19];
    float* out = (float*)d_out;

    // workspace layout (float units; 16B-aligned); ~45 MB
    float* ws  = (float*)d_ws;
    float* h      = ws;                                  // 1,048,576 f
    float2* stats = (float2*)(h + (size_t)BLP_*DM_);     // 4*BLP_ float2
    float* bn     = (float*)(stats + 4*BLP_);            // 64,000 f (b,l,n)
    float* cn     = bn + (size_t)B_*L_*DS_;              // 64,000 f
    float* send   = cn + (size_t)B_*L_*DS_;              // 2,048,000 f
    float* aprod  = send + (size_t)B_*DI_*DS_*NC_;       // 2,048,000 f
    ushort_t* xz_bf = (ushort_t*)(aprod + (size_t)B_*DI_*DS_*NC_); // BLP_*1024 us
    ushort_t* u_bf  = xz_bf + (size_t)BLP_*1024;         // BLP_*DI_ us
    ushort_t* ysbb  = u_bf + (size_t)BLP_*DI_;           // BLP_*DI_ us
    ushort_t* dtn   = ysbb + (size_t)BLP_*DI_;           // B_*L_*DI_ us (bf16)
    ushort_t* ipwb  = dtn + (size_t)B_*L_*DI_;           // NL_*1024*DM_ us
    ushort_t* opwb  = ipwb + (size_t)NL_*1024*DM_;       // NL_*DM_*DI_ us
    ushort_t* xpwb  = opwb + (size_t)NL_*DM_*DI_;        // NL_*48*512 us

    // convert all weights to bf16 in one launch
    const int N0 = NL_*1024*DM_/4, N1 = NL_*DM_*DI_/4, N2 = NL_*48*512/4;
    f2bf3_kernel<<<(N0+N1+N2 + 255)/256, 256, 0, stream>>>(
        ipw, opw, xpw, ipwb, opwb, xpwb, N0, N1, N2);

    embed_kernel<<<BL_, 256, 0, stream>>>(x, biw, bib, ge, me, h, stats);
    for (int i = 0; i < NL_; i++) {
        gemm_ln_mfma<<<dim3(BLP_/128, 1024/128), 256, 0, stream>>>(
            h, stats, lnw + i*DM_, lnb + i*DM_,
            ipwb + (size_t)i*1024*DM_, xz_bf, 1024);
        conv_xproj_kernel<<<dim3(NC_, B_), 256, 0, stream>>>(
            xz_bf, cw + i*DI_*4, cb + i*DI_, xpwb + (size_t)i*48*512,
            dtw + (size_t)i*DI_*16, dtb + i*DI_, alog + (size_t)i*DI_*DS_,
            u_bf, bn, cn, dtn, send, aprod);
        scan_phase2<<<B_*DI_*DS_/256, 256, 0, stream>>>(send, aprod);
        scan_phase3<<<dim3(NC_, DI_/128, B_), 128, 0, stream>>>(
            dtn, u_bf, bn, cn, alog + (size_t)i*DI_*DS_, Dv + i*DI_,
            send, xz_bf, ysbb);
        gemm_out_mfma<<<dim3(BLP_/128, DM_/128), 256, 0, stream>>>(
            ysbb, opwb + (size_t)i*DM_*DI_, h, DM_, DI_, stats);
    }
    final_kernel<<<BL_, 256, 0, stream>>>(h, fw, fb, hw, hb, out);
}

// Round 18
// 472.175 us; speedup vs baseline: 1.7540x; 1.0107x over previous
//
#include <hip/hip_runtime.h>
#include <math.h>

#define B_  2
#define L_  2000
#define DM_ 256
#define DI_ 512
#define DS_ 16
#define NL_ 4
#define BL_ (B_*L_)     // 4000
#define BLP_ 4096       // rows padded to multiple of 64
#define NC_ 125         // scan chunks == conv strips (CL=16)
#define CL_ 16          // chunk length == conv_xproj strip

typedef unsigned short ushort_t;
typedef __attribute__((ext_vector_type(8))) short bf16x8;
typedef __attribute__((ext_vector_type(4))) float f32x4;

__device__ __forceinline__ float siluf(float x) {
    return x / (1.f + __expf(-x));
}

__device__ __forceinline__ ushort_t f2bf(float x) {
    unsigned int u = __float_as_uint(x);
    unsigned int r = (u + 0x7FFFu + ((u >> 16) & 1u)) >> 16;
    return (ushort_t)r;
}

__device__ __forceinline__ float bf2f(ushort_t v) {
    return __uint_as_float(((unsigned int)v) << 16);
}

// ---- merged embed (blocks 0..BL_-1) + weight f2bf (remaining blocks) ----
// embed: h = x*biw + bib + ge + me; emits row LN stats (slot 0; slots 1-3 zeroed).
// f2bf: converts ipw/opw/xpw to bf16, 4 elements per thread.
__global__ __launch_bounds__(256) void embed_f2bf_kernel(
    const float* __restrict__ x, const float* __restrict__ biw,
    const float* __restrict__ bib, const float* __restrict__ ge,
    const float* __restrict__ me, float* __restrict__ h,
    float2* __restrict__ stats,
    const float* __restrict__ s0, const float* __restrict__ s1,
    const float* __restrict__ s2, ushort_t* __restrict__ d0,
    ushort_t* __restrict__ d1, ushort_t* __restrict__ d2,
    int N0, int N1, int N2)
{
    if (blockIdx.x < BL_) {
        __shared__ float sm[8];
        int bl = blockIdx.x, d = threadIdx.x;
        int l = bl % L_;
        float v = x[bl]*biw[d] + bib[d] + ge[(size_t)l*DM_ + d] + me[d];
        h[(size_t)bl*DM_ + d] = v;
        float s = v, q = v*v;
        #pragma unroll
        for (int o = 32; o > 0; o >>= 1) {
            s += __shfl_down(s, o);
            q += __shfl_down(q, o);
        }
        if ((d & 63) == 0) { sm[d >> 6] = s; sm[4 + (d >> 6)] = q; }
        __syncthreads();
        if (d == 0) {
            stats[bl] = make_float2(sm[0]+sm[1]+sm[2]+sm[3], sm[4]+sm[5]+sm[6]+sm[7]);
            stats[BLP_ + bl]   = make_float2(0.f, 0.f);
            stats[2*BLP_ + bl] = make_float2(0.f, 0.f);
            stats[3*BLP_ + bl] = make_float2(0.f, 0.f);
        }
    } else {
        int i = (blockIdx.x - BL_)*256 + threadIdx.x;
        const float* s; ushort_t* d; int j;
        if (i < N0)           { s = s0; d = d0; j = i; }
        else if (i < N0+N1)   { s = s1; d = d1; j = i - N0; }
        else if (i < N0+N1+N2){ s = s2; d = d2; j = i - N0 - N1; }
        else return;
        float4 v = *(const float4*)(s + 4*j);
        ushort_t o[4] = {f2bf(v.x), f2bf(v.y), f2bf(v.z), f2bf(v.w)};
        *(ushort2*)(d + 4*j)     = *(ushort2*)&o[0];
        *(ushort2*)(d + 4*j + 2) = *(ushort2*)&o[2];
    }
}

// ---------------- fused LN + in_proj MFMA GEMM ----------------
__global__ __launch_bounds__(256) void gemm_ln_mfma(
    const float* __restrict__ H, const float2* __restrict__ stats,
    const float* __restrict__ lnw, const float* __restrict__ lnb,
    const ushort_t* __restrict__ W, ushort_t* __restrict__ C, int ldc)
{
    __shared__ ushort_t a_s[128*64];
    __shared__ ushort_t b_s[128*64];
    const int r0 = blockIdx.x*128, c0 = blockIdx.y*128;
    const int tid = threadIdx.x;
    const int lane = tid & 63, w = tid >> 6;
    const int wm = (w & 1)*64, wn = (w >> 1)*64;
    const int qd = lane >> 4, l16 = lane & 15;
    f32x4 acc[4][4] = {};
    for (int kc = 0; kc < DM_; kc += 64) {
        #pragma unroll
        for (int q = 0; q < 4; q++) {
            int ch = tid + 256*q;              // 0..1023
            int row = ch >> 3, col8 = (ch & 7)*8;
            int grow = r0 + row;
            float2 t0 = stats[grow], t1 = stats[BLP_ + grow];
            float2 t2 = stats[2*BLP_ + grow], t3 = stats[3*BLP_ + grow];
            float sum = t0.x + t1.x + t2.x + t3.x;
            float ssq = t0.y + t1.y + t2.y + t3.y;
            float mu  = sum * (1.f/DM_);
            float inv = rsqrtf(fmaxf(ssq*(1.f/DM_) - mu*mu, 0.f) + 1e-5f);
            const float* hp = H + (size_t)grow*DM_ + kc + col8;
            float4 h0 = *(const float4*)hp, h1 = *(const float4*)(hp + 4);
            const float* wp = lnw + kc + col8;
            const float* bp = lnb + kc + col8;
            float4 w0 = *(const float4*)wp, w1 = *(const float4*)(wp + 4);
            float4 b0 = *(const float4*)bp, b1 = *(const float4*)(bp + 4);
            __align__(16) ushort_t o[8];
            o[0] = f2bf((h0.x - mu)*inv*w0.x + b0.x);
            o[1] = f2bf((h0.y - mu)*inv*w0.y + b0.y);
            o[2] = f2bf((h0.z - mu)*inv*w0.z + b0.z);
            o[3] = f2bf((h0.w - mu)*inv*w0.w + b0.w);
            o[4] = f2bf((h1.x - mu)*inv*w1.x + b1.x);
            o[5] = f2bf((h1.y - mu)*inv*w1.y + b1.y);
            o[6] = f2bf((h1.z - mu)*inv*w1.z + b1.z);
            o[7] = f2bf((h1.w - mu)*inv*w1.w + b1.w);
            *(uint4*)&a_s[row*64 + col8] = *(const uint4*)o;
            *(bf16x8*)&b_s[row*64 + col8] =
                *(const bf16x8*)(W + (size_t)(c0 + row)*DM_ + kc + col8);
        }
        __syncthreads();
        #pragma unroll
        for (int ks = 0; ks < 2; ks++) {
            bf16x8 af[4], bf[4];
            #pragma unroll
            for (int i = 0; i < 4; i++)
                af[i] = *(const bf16x8*)&a_s[(wm + i*16 + l16)*64 + ks*32 + qd*8];
            #pragma unroll
            for (int j = 0; j < 4; j++)
                bf[j] = *(const bf16x8*)&b_s[(wn + j*16 + l16)*64 + ks*32 + qd*8];
            #pragma unroll
            for (int i = 0; i < 4; i++) {
                #pragma unroll
                for (int j = 0; j < 4; j++)
                    acc[i][j] = __builtin_amdgcn_mfma_f32_16x16x32_bf16(
                        af[i], bf[j], acc[i][j], 0, 0, 0);
            }
        }
        __syncthreads();
    }
    #pragma unroll
    for (int i = 0; i < 4; i++) {
        #pragma unroll
        for (int j = 0; j < 4; j++) {
            #pragma unroll
            for (int r = 0; r < 4; r++) {
                int row = r0 + wm + i*16 + qd*4 + r;
                int col = c0 + wn + j*16 + l16;
                C[(size_t)row*ldc + col] = f2bf(acc[i][j][r]);
            }
        }
    }
}

// ---------------- out_proj MFMA GEMM with h += and LN-stats epilogue ----------------
__global__ __launch_bounds__(256) void gemm_out_mfma(
    const ushort_t* __restrict__ A, const ushort_t* __restrict__ W,
    float* __restrict__ C, int ldc, int K, float2* __restrict__ stp)
{
    __shared__ ushort_t a_s[128*64];
    __shared__ ushort_t b_s[128*64];
    const int r0 = blockIdx.x*128, c0 = blockIdx.y*128;
    const int tid = threadIdx.x;
    const int lane = tid & 63, w = tid >> 6;
    const int wm = (w & 1)*64, wn = (w >> 1)*64;
    const int qd = lane >> 4, l16 = lane & 15;
    f32x4 acc[4][4] = {};
    for (int kc = 0; kc < K; kc += 64) {
        #pragma unroll
        for (int q = 0; q < 4; q++) {
            int ch = tid + 256*q;
            int row = ch >> 3, col8 = (ch & 7)*8;
            *(bf16x8*)&a_s[row*64 + col8] =
                *(const bf16x8*)(A + (size_t)(r0 + row)*K + kc + col8);
            *(bf16x8*)&b_s[row*64 + col8] =
                *(const bf16x8*)(W + (size_t)(c0 + row)*K + kc + col8);
        }
        __syncthreads();
        #pragma unroll
        for (int ks = 0; ks < 2; ks++) {
            bf16x8 af[4], bf[4];
            #pragma unroll
            for (int i = 0; i < 4; i++)
                af[i] = *(const bf16x8*)&a_s[(wm + i*16 + l16)*64 + ks*32 + qd*8];
            #pragma unroll
            for (int j = 0; j < 4; j++)
                bf[j] = *(const bf16x8*)&b_s[(wn + j*16 + l16)*64 + ks*32 + qd*8];
            #pragma unroll
            for (int i = 0; i < 4; i++) {
                #pragma unroll
                for (int j = 0; j < 4; j++)
                    acc[i][j] = __builtin_amdgcn_mfma_f32_16x16x32_bf16(
                        af[i], bf[j], acc[i][j], 0, 0, 0);
            }
        }
        __syncthreads();
    }
    const int slot = blockIdx.y*2 + (w >> 1);
    #pragma unroll
    for (int i = 0; i < 4; i++) {
        #pragma unroll
        for (int r = 0; r < 4; r++) {
            int row = r0 + wm + i*16 + qd*4 + r;
            float sum = 0.f, ssq = 0.f;
            #pragma unroll
            for (int j = 0; j < 4; j++) {
                int col = c0 + wn + j*16 + l16;
                size_t idx = (size_t)row*ldc + col;
                float v = C[idx] + acc[i][j][r];
                C[idx] = v;
                sum += v; ssq += v*v;
            }
            sum += __shfl_xor(sum, 1); ssq += __shfl_xor(ssq, 1);
            sum += __shfl_xor(sum, 2); ssq += __shfl_xor(ssq, 2);
            sum += __shfl_xor(sum, 4); ssq += __shfl_xor(ssq, 4);
            sum += __shfl_xor(sum, 8); ssq += __shfl_xor(ssq, 8);
            if (l16 == 0) stp[(size_t)slot*BLP_ + row] = make_float2(sum, ssq);
        }
    }
}

// ---- fused conv(4)+silu + x_proj MFMA + dt_proj + scan phase1 ----
__global__ __launch_bounds__(256) void conv_xproj_kernel(
    const ushort_t* __restrict__ xz, const float* __restrict__ cw,
    const float* __restrict__ cb, const ushort_t* __restrict__ XWb,
    const float* __restrict__ DTW, const float* __restrict__ DTB,
    const float* __restrict__ Alog,
    ushort_t* __restrict__ u_bf, float* __restrict__ bn,
    float* __restrict__ cn, ushort_t* __restrict__ dtn,
    float* __restrict__ send, float* __restrict__ aprod)
{
    __shared__ ushort_t xs[19][520];
    __shared__ ushort_t us[16][520];
    __shared__ float ps[4*16*48];
    __shared__ float dtr_s[16][16];
    const int c = blockIdx.x, b = blockIdx.y;
    const int l0 = c * 16;
    const int tid = threadIdx.x;
    const int lane = tid & 63, w = tid >> 6;
    const int qd = lane >> 4, l16 = lane & 15;
    for (int f = tid; f < 19*64; f += 256) {
        int row = f >> 6, c8 = (f & 63)*8;
        int l = l0 - 3 + row;
        uint4 v = {0u, 0u, 0u, 0u};
        if (l >= 0)
            v = *(const uint4*)(xz + (size_t)(b*L_ + l)*1024 + c8);
        *(uint4*)&xs[row][c8] = v;
    }
    __syncthreads();
    #pragma unroll
    for (int q = 0; q < 2; q++) {
        int ch = tid + q*256;
        float4 wv = *(const float4*)(cw + ch*4);
        float bias = cb[ch];
        float x0 = bf2f(xs[0][ch]);
        float x1 = bf2f(xs[1][ch]);
        float x2 = bf2f(xs[2][ch]);
        #pragma unroll
        for (int j = 0; j < 16; j++) {
            float x3 = bf2f(xs[3 + j][ch]);
            float v = fmaf(x0, wv.x, fmaf(x1, wv.y, fmaf(x2, wv.z, fmaf(x3, wv.w, bias))));
            us[j][ch] = f2bf(siluf(v));
            x0 = x1; x1 = x2; x2 = x3;
        }
    }
    __syncthreads();
    for (int f = tid; f < 16*64; f += 256) {
        int row = f >> 6, c8 = (f & 63)*8;
        *(uint4*)(u_bf + (size_t)(b*L_ + l0 + row)*512 + c8) =
            *(const uint4*)&us[row][c8];
    }
    f32x4 acc[3] = {};
    #pragma unroll
    for (int step = 0; step < 4; step++) {
        int k = w*128 + step*32 + qd*8;
        bf16x8 af = *(const bf16x8*)&us[l16][k];
        #pragma unroll
        for (int j = 0; j < 3; j++) {
            bf16x8 bf = *(const bf16x8*)(XWb + (size_t)(j*16 + l16)*512 + k);
            acc[j] = __builtin_amdgcn_mfma_f32_16x16x32_bf16(af, bf, acc[j], 0, 0, 0);
        }
    }
    #pragma unroll
    for (int j = 0; j < 3; j++) {
        #pragma unroll
        for (int r = 0; r < 4; r++)
            ps[(w*16 + qd*4 + r)*48 + j*16 + l16] = acc[j][r];
    }
    __syncthreads();
    #pragma unroll
    for (int e = tid; e < 768; e += 256)
        ps[e] = ps[e] + ps[768 + e] + ps[1536 + e] + ps[2304 + e];
    __syncthreads();
    {
        int row = tid >> 4, n = tid & 15;
        dtr_s[row][n] = ps[row*48 + n];
        size_t base = ((size_t)(b*L_) + l0 + row)*DS_ + n;
        bn[base] = ps[row*48 + 16 + n];
        cn[base] = ps[row*48 + 32 + n];
    }
    __syncthreads();
    #pragma unroll
    for (int q = 0; q < 2; q++) {
        int d = tid + q*256;
        float wreg[16];
        const float4* wp = (const float4*)(DTW + (size_t)d*16);
        #pragma unroll
        for (int k4 = 0; k4 < 4; k4++) {
            float4 v = wp[k4];
            wreg[4*k4+0] = v.x; wreg[4*k4+1] = v.y;
            wreg[4*k4+2] = v.z; wreg[4*k4+3] = v.w;
        }
        float bias = DTB[d];
        float dtv[16];
        #pragma unroll
        for (int r = 0; r < 16; r++) {
            float a = bias;
            #pragma unroll
            for (int k = 0; k < 16; k++) a = fmaf(dtr_s[r][k], wreg[k], a);
            float dt = a > 20.f ? a : log1pf(__expf(a));
            ushort_t dtb16 = f2bf(dt);
            dtn[((size_t)(b*L_) + l0 + r)*DI_ + d] = dtb16;
            dtv[r] = bf2f(dtb16);              // phase1 uses same value as phase3
        }
        float Ac[DS_], s[DS_], ap[DS_];
        const float* ar = Alog + (size_t)d*DS_;
        #pragma unroll
        for (int n = 0; n < DS_; n++) { Ac[n] = -__expf(ar[n]); s[n] = 0.f; ap[n] = 1.f; }
        #pragma unroll
        for (int l = 0; l < 16; l++) {
            float dt = dtv[l];
            float u  = bf2f(us[l][d]);
            float dtu = dt*u;
            #pragma unroll
            for (int n = 0; n < DS_; n++) {
                float e = __expf(dt*Ac[n]);
                s[n] = fmaf(e, s[n], dtu*ps[l*48 + 16 + n]);   // broadcast read
                ap[n] *= e;
            }
        }
        size_t base = (((size_t)c*B_ + b)*DI_ + d)*DS_;
        #pragma unroll
        for (int n4 = 0; n4 < 4; n4++) {
            *(float4*)(send  + base + 4*n4) = *(float4*)&s[4*n4];
            *(float4*)(aprod + base + 4*n4) = *(float4*)&ap[4*n4];
        }
    }
}

__global__ __launch_bounds__(256) void scan_phase2(
    float* __restrict__ send, const float* __restrict__ aprod)
{
    int t = blockIdx.x*256 + threadIdx.x;   // B_*DI_*DS_ = 16384 threads
    float s = 0.f;
    for (int c = 0; c < NC_; c++) {
        size_t idx = (size_t)c*(B_*DI_*DS_) + t;         // coalesced per c
        float tmp = send[idx];
        send[idx] = s;
        s = fmaf(aprod[idx], s, tmp);
    }
}

// Phase 3: re-run chunk with incoming state; fuse (y + u*D)*silu(z) -> bf16.
__global__ __launch_bounds__(128) void scan_phase3(
    const ushort_t* __restrict__ dtn, const ushort_t* __restrict__ u_bf,
    const float* __restrict__ bn, const float* __restrict__ cn,
    const float* __restrict__ Alog, const float* __restrict__ Dv,
    const float* __restrict__ sin_, const ushort_t* __restrict__ xz,
    ushort_t* __restrict__ ysb)
{
    __shared__ float b_sh[CL_*DS_];
    __shared__ float c_sh[CL_*DS_];
    const int c = blockIdx.x, qy = blockIdx.y, b = blockIdx.z;
    const int tid = threadIdx.x;
    const int d = qy*128 + tid;
    const int l0 = c*CL_;
    for (int f = tid; f < CL_*DS_; f += 128) {
        size_t src = ((size_t)(b*L_) + l0)*DS_ + f;
        b_sh[f] = bn[src];
        c_sh[f] = cn[src];
    }
    float Ac[DS_], s[DS_];
    const float* ar = Alog + (size_t)d*DS_;
    #pragma unroll
    for (int n = 0; n < DS_; n++) Ac[n] = -__expf(ar[n]);
    {
        size_t base = (((size_t)c*B_ + b)*DI_ + d)*DS_;
        #pragma unroll
        for (int n4 = 0; n4 < 4; n4++)
            *(float4*)&s[4*n4] = *(const float4*)(sin_ + base + 4*n4);
    }
    const float Dd = Dv[d];
    __syncthreads();
    const ushort_t* dtp = dtn  + ((size_t)(b*L_ + l0))*DI_ + d;
    const ushort_t* up  = u_bf + ((size_t)(b*L_ + l0))*DI_ + d;
    const ushort_t* zp  = xz   + ((size_t)(b*L_ + l0))*1024 + 512 + d;
    ushort_t*       yo  = ysb  + ((size_t)(b*L_ + l0))*DI_ + d;
    for (int l = 0; l < CL_; l++) {
        float dt = bf2f(dtp[(size_t)l*DI_]);
        float u  = bf2f(up[(size_t)l*DI_]);
        float z  = bf2f(zp[(size_t)l*1024]);
        float dtu = dt*u;
        float bv[DS_], cv[DS_];
        #pragma unroll
        for (int n4 = 0; n4 < 4; n4++) {
            *(float4*)&bv[4*n4] = *(const float4*)&b_sh[l*DS_ + 4*n4];
            *(float4*)&cv[4*n4] = *(const float4*)&c_sh[l*DS_ + 4*n4];
        }
        float y = u*Dd;
        #pragma unroll
        for (int n = 0; n < DS_; n++) {
            float e = __expf(dt*Ac[n]);
            s[n] = fmaf(e, s[n], dtu*bv[n]);
            y = fmaf(s[n], cv[n], y);
        }
        yo[(size_t)l*DI_] = f2bf(y * siluf(z));
    }
}

// ---------------- final LN + head dot ----------------
__global__ __launch_bounds__(256) void final_kernel(
    const float* __restrict__ h, const float* __restrict__ fw,
    const float* __restrict__ fb, const float* __restrict__ hw,
    const float* __restrict__ hb, float* __restrict__ out)
{
    __shared__ float sm[4];
    int row = blockIdx.x, tid = threadIdx.x;
    float v = h[(size_t)row*DM_ + tid];
    float s = v;
    #pragma unroll
    for (int o = 32; o > 0; o >>= 1) s += __shfl_down(s, o);
    if ((tid & 63) == 0) sm[tid >> 6] = s;
    __syncthreads();
    float mu = (sm[0]+sm[1]+sm[2]+sm[3]) * (1.f/DM_);
    __syncthreads();
    float dv = v - mu;
    float q = dv*dv;
    #pragma unroll
    for (int o = 32; o > 0; o >>= 1) q += __shfl_down(q, o);
    if ((tid & 63) == 0) sm[tid >> 6] = q;
    __syncthreads();
    float var = (sm[0]+sm[1]+sm[2]+sm[3]) * (1.f/DM_);
    float nv = dv * rsqrtf(var + 1e-5f) * fw[tid] + fb[tid];
    float p = nv * hw[tid];
    __syncthreads();
    #pragma unroll
    for (int o = 32; o > 0; o >>= 1) p += __shfl_down(p, o);
    if ((tid & 63) == 0) sm[tid >> 6] = p;
    __syncthreads();
    if (tid == 0) out[row] = sm[0]+sm[1]+sm[2]+sm[3] + hb[0];
}

extern "C" void kernel_launch(void* const* d_in, const int* in_sizes, int n_in,
                              void* d_out, int out_size, void* d_ws, size_t ws_size,
                              hipStream_t stream)
{
    const float* x    = (const float*)d_in[0];
    const float* biw  = (const float*)d_in[1];
    const float* bib  = (const float*)d_in[2];
    const float* ge   = (const float*)d_in[3];
    const float* me   = (const float*)d_in[4];
    const float* lnw  = (const float*)d_in[5];
    const float* lnb  = (const float*)d_in[6];
    const float* ipw  = (const float*)d_in[7];
    const float* cw   = (const float*)d_in[8];
    const float* cb   = (const float*)d_in[9];
    const float* xpw  = (const float*)d_in[10];
    const float* dtw  = (const float*)d_in[11];
    const float* dtb  = (const float*)d_in[12];
    const float* alog = (const float*)d_in[13];
    const float* Dv   = (const float*)d_in[14];
    const float* opw  = (const float*)d_in[15];
    const float* fw   = (const float*)d_in[16];
    const float* fb   = (const float*)d_in[17];
    const float* hw   = (const float*)d_in[18];
    const float* hb   = (const float*)d_in[19];
    float* out = (float*)d_out;

    // workspace layout (float units; 16B-aligned); ~45 MB
    float* ws  = (float*)d_ws;
    float* h      = ws;                                  // 1,048,576 f
    float2* stats = (float2*)(h + (size_t)BLP_*DM_);     // 4*BLP_ float2
    float* bn     = (float*)(stats + 4*BLP_);            // 64,000 f (b,l,n)
    float* cn     = bn + (size_t)B_*L_*DS_;              // 64,000 f
    float* send   = cn + (size_t)B_*L_*DS_;              // 2,048,000 f
    float* aprod  = send + (size_t)B_*DI_*DS_*NC_;       // 2,048,000 f
    ushort_t* xz_bf = (ushort_t*)(aprod + (size_t)B_*DI_*DS_*NC_); // BLP_*1024 us
    ushort_t* u_bf  = xz_bf + (size_t)BLP_*1024;         // BLP_*DI_ us
    ushort_t* ysbb  = u_bf + (size_t)BLP_*DI_;           // BLP_*DI_ us
    ushort_t* dtn   = ysbb + (size_t)BLP_*DI_;           // B_*L_*DI_ us (bf16)
    ushort_t* ipwb  = dtn + (size_t)B_*L_*DI_;           // NL_*1024*DM_ us
    ushort_t* opwb  = ipwb + (size_t)NL_*1024*DM_;       // NL_*DM_*DI_ us
    ushort_t* xpwb  = opwb + (size_t)NL_*DM_*DI_;        // NL_*48*512 us

    // merged embed + weight conversion (independent work, one chain link)
    const int N0 = NL_*1024*DM_/4, N1 = NL_*DM_*DI_/4, N2 = NL_*48*512/4;
    const int conv_blocks = (N0+N1+N2 + 255)/256;
    embed_f2bf_kernel<<<BL_ + conv_blocks, 256, 0, stream>>>(
        x, biw, bib, ge, me, h, stats,
        ipw, opw, xpw, ipwb, opwb, xpwb, N0, N1, N2);

    for (int i = 0; i < NL_; i++) {
        gemm_ln_mfma<<<dim3(BLP_/128, 1024/128), 256, 0, stream>>>(
            h, stats, lnw + i*DM_, lnb + i*DM_,
            ipwb + (size_t)i*1024*DM_, xz_bf, 1024);
        conv_xproj_kernel<<<dim3(NC_, B_), 256, 0, stream>>>(
            xz_bf, cw + i*DI_*4, cb + i*DI_, xpwb + (size_t)i*48*512,
            dtw + (size_t)i*DI_*16, dtb + i*DI_, alog + (size_t)i*DI_*DS_,
            u_bf, bn, cn, dtn, send, aprod);
        scan_phase2<<<B_*DI_*DS_/256, 256, 0, stream>>>(send, aprod);
        scan_phase3<<<dim3(NC_, DI_/128, B_), 128, 0, stream>>>(
            dtn, u_bf, bn, cn, alog + (size_t)i*DI_*DS_, Dv + i*DI_,
            send, xz_bf, ysbb);
        gemm_out_mfma<<<dim3(BLP_/128, DM_/128), 256, 0, stream>>>(
            ysbb, opwb + (size_t)i*DM_*DI_, h, DM_, DI_, stats);
    }
    final_kernel<<<BL_, 256, 0, stream>>>(h, fw, fb, hw, hb, out);
}